// Round 3
// baseline (331.620 us; speedup 1.0000x reference)
//
#include <hip/hip_runtime.h>

typedef float v2f __attribute__((ext_vector_type(2)));

#define NB 16
#define NC 256
#define NS 64
#define NL 4096

// Fused kernel: params + recurrent scan, 2 batches per wave (ILP-2).
// One 64-lane wave per (c, batch-pair); lane = state s.
// State g = 2*b*h folded:  g[n] = w*g[n-1] + (2b)*x[n];  y[n] = sum_s Re(g_s[n])
__global__ __launch_bounds__(64, 2) void s4d_fused(const float* __restrict__ x,
                                                   const float* __restrict__ log_dt,
                                                   const float* __restrict__ a_real,
                                                   const float* __restrict__ a_imag,
                                                   const float* __restrict__ cv,
                                                   float* __restrict__ y) {
    const int blk = blockIdx.x;            // 2048 = NC * NB/2
    const int c = blk & (NC - 1);
    const int bp = blk >> 8;               // batch pair 0..7
    const int lane = threadIdx.x;          // state s

    // ---- inline per-(c,s) params (identical arithmetic to the passing version) ----
    const int i = c * NS + lane;
    const float dt = expf(log_dt[c]);
    const float ar = -expf(a_real[i]);
    const float ai = a_imag[i];
    const float adr = ar * dt, adi = ai * dt;
    const float e = expf(adr);
    float sn, cs;
    sincosf(adi, &sn, &cs);
    const float wr = e * cs, wi = e * sn;            // w = exp(a*dt)
    const float inv = 1.0f / (ar * ar + ai * ai);
    const float numr = wr - 1.0f, numi = wi;
    const float qr = (numr * ar + numi * ai) * inv;
    const float qi = (numi * ar - numr * ai) * inv;
    const float c0 = cv[2 * i], c1 = cv[2 * i + 1];
    const float br = c0 * qr - c1 * qi;
    const float bi = c0 * qi + c1 * qr;
    const v2f w1 = {wr, wi};                          // (wr,  wi)
    const v2f w2 = {-wi, wr};                         // (-wi, wr)
    const v2f b2 = {2.0f * br, 2.0f * bi};            // (2br, 2bi)

    const int b0 = bp * 2, b1 = bp * 2 + 1;
    const float* xp0 = x + ((size_t)b0 * NC + c) * NL;
    const float* xp1 = x + ((size_t)b1 * NC + c) * NL;
    float* yp0 = y + ((size_t)b0 * NC + c) * NL;
    float* yp1 = y + ((size_t)b1 * NC + c) * NL;

    __shared__ float2 xs[64];              // (x_b0, x_b1) per step -> one ds_read_b64
    __shared__ float rs[2][32][65];        // [batch][t][s], pad 65 -> conflict-free

    v2f g0 = {0.0f, 0.0f}, g1 = {0.0f, 0.0f};
    float xn0 = xp0[lane], xn1 = xp1[lane];           // prefetch tile 0

    const int bb = lane >> 5, tt = lane & 31;         // reduction role
    float* ypb = bb ? yp1 : yp0;
    const float* row = &rs[bb][tt][0];

    for (int tile = 0; tile < 64; ++tile) {
        xs[lane] = make_float2(xn0, xn1);  // prev tile's readers done (trailing barrier)
        __syncthreads();
        if (tile < 63) {                   // prefetch next tile
            xn0 = xp0[(tile + 1) * 64 + lane];
            xn1 = xp1[(tile + 1) * 64 + lane];
        }

        for (int sub = 0; sub < 2; ++sub) {
            const int base = sub * 32;
#pragma unroll
            for (int t = 0; t < 32; ++t) {
                float2 xv = xs[base + t];               // uniform ds_read_b64
                v2f n0 = w1 * g0.xx + b2 * xv.x;
                g0 = w2 * g0.yy + n0;                   // g0' = w*g0 + 2b*x0
                rs[0][t][lane] = g0.x;
                v2f n1 = w1 * g1.xx + b2 * xv.y;
                g1 = w2 * g1.yy + n1;                   // g1' = w*g1 + 2b*x1
                rs[1][t][lane] = g1.x;
            }
            __syncthreads();
            // transpose-reduce: lane -> (batch = lane>>5, t = lane&31), sum 64 states
            float a0 = 0.f, a1 = 0.f, a2 = 0.f, a3 = 0.f;
#pragma unroll
            for (int k = 0; k < 64; k += 4) {
                a0 += row[k + 0];
                a1 += row[k + 1];
                a2 += row[k + 2];
                a3 += row[k + 3];
            }
            ypb[tile * 64 + base + tt] = (a0 + a1) + (a2 + a3);  // 128B per half-wave
            __syncthreads();               // protect rs (and xs at tile end)
        }
    }
}

extern "C" void kernel_launch(void* const* d_in, const int* in_sizes, int n_in,
                              void* d_out, int out_size, void* d_ws, size_t ws_size,
                              hipStream_t stream) {
    const float* x      = (const float*)d_in[0];
    const float* log_dt = (const float*)d_in[1];
    const float* a_real = (const float*)d_in[2];
    const float* a_imag = (const float*)d_in[3];
    const float* cv     = (const float*)d_in[4];
    float* yv = (float*)d_out;

    hipLaunchKernelGGL(s4d_fused, dim3(NC * NB / 2), dim3(64), 0, stream,
                       x, log_dt, a_real, a_imag, cv, yv);
}

// Round 4
// 168.763 us; speedup vs baseline: 1.9650x; 1.9650x over previous
//
#include <hip/hip_runtime.h>

typedef __attribute__((ext_vector_type(8))) short bf16x8;
typedef __attribute__((ext_vector_type(4))) short short4v;
typedef __attribute__((ext_vector_type(4))) float f32x4;

#define NB 16
#define NC 256
#define NS 64
#define NL 4096
#define Q  64
#define NQ (NL / Q)

// LDS byte offsets
#define OFF_T   0        // 64x64 bf16 [t][m]   (A-operand, swizzled)
#define OFF_WR  8192     // 64x64 bf16 [s][m]
#define OFF_WI  16384
#define OFF_VR  24576    // 64x64 bf16 [t][s]
#define OFF_VM  32768
#define OFF_X   40960    // 16x64 bf16 [b][m]   (B-operand, swizzled)
#define OFF_HR  43008    // 16x64 bf16 [b][s]
#define OFF_HI  45056
#define OFF_PAR 47104    // adr[64], adi[64], b2r[64], b2i[64] floats
#define OFF_K   48128    // k[64] floats
#define OFF_KP  48384    // kpart[4][64] floats
#define LDS_SZ  49408

__device__ __forceinline__ int swz(int row, int bytecol) {
    return (row * 128 + bytecol) ^ ((row & 7) << 4);
}
__device__ __forceinline__ short f2bf(float f) {            // RNE float->bf16
    unsigned u = __builtin_bit_cast(unsigned, f);
    u = (u + 0x7FFFu + ((u >> 16) & 1u)) >> 16;
    return (short)u;
}

__global__ __launch_bounds__(256, 1) void s4d_mfma(const float* __restrict__ x,
                                                   const float* __restrict__ log_dt,
                                                   const float* __restrict__ a_real,
                                                   const float* __restrict__ a_imag,
                                                   const float* __restrict__ cv,
                                                   float* __restrict__ y) {
    __shared__ __align__(16) char lds[LDS_SZ];
    const int c = blockIdx.x;
    const int tid = threadIdx.x;
    const int l = tid & 63, w = tid >> 6;

    float* parF = (float*)(lds + OFF_PAR);
    float* kF   = (float*)(lds + OFF_K);
    float* kpF  = (float*)(lds + OFF_KP);

    // ---- stage 0: per-s params (identical arithmetic to verified scan) ----
    if (tid < 64) {
        int s = tid;
        float dt = expf(log_dt[c]);
        float ar = -expf(a_real[c * 64 + s]);
        float ai = a_imag[c * 64 + s];
        float adr = ar * dt, adi = ai * dt;
        float e = expf(adr), sn, cs;
        sincosf(adi, &sn, &cs);
        float wr = e * cs, wi = e * sn;
        float inv = 1.0f / (ar * ar + ai * ai);
        float numr = wr - 1.0f, numi = wi;
        float qr = (numr * ar + numi * ai) * inv;
        float qi = (numi * ar - numr * ai) * inv;
        float c0 = cv[2 * (c * 64 + s)], c1 = cv[2 * (c * 64 + s) + 1];
        float br = c0 * qr - c1 * qi;
        float bi = c0 * qi + c1 * qr;
        parF[s] = adr; parF[64 + s] = adi;
        parF[128 + s] = 2.0f * br; parF[192 + s] = 2.0f * bi;
    }
    __syncthreads();

    // ---- stage 1: k[d] = sum_s 2Re(b_s w_s^d), 4-way partial over s ----
    {
        int d = tid & 63, part = tid >> 6;
        float ps = 0.0f;
        for (int s = part * 16; s < part * 16 + 16; ++s) {
            float e = expf(parF[s] * (float)d), sn, cs;
            sincosf(parF[64 + s] * (float)d, &sn, &cs);
            ps += e * (parF[128 + s] * cs - parF[192 + s] * sn);
        }
        kpF[part * 64 + d] = ps;
    }
    __syncthreads();
    if (tid < 64) kF[tid] = kpF[tid] + kpF[64 + tid] + kpF[128 + tid] + kpF[192 + tid];
    __syncthreads();

    // ---- stage 2: fill T, W, V; stage X0; zero H ----
    {   // T[t][m] = k[t-m] (t>=m) else 0
        int t = tid >> 2, m0 = (tid & 3) * 16;
        for (int m = m0; m < m0 + 16; ++m) {
            float v = (t >= m) ? kF[t - m] : 0.0f;
            *(short*)(lds + OFF_T + swz(t, m * 2)) = f2bf(v);
        }
    }
    {   // W[s][m] = w_s^(63-m)
        int s = tid >> 2, m0 = (tid & 3) * 16;
        float adr = parF[s], adi = parF[64 + s];
        for (int m = m0; m < m0 + 16; ++m) {
            float p = (float)(63 - m);
            float e = expf(adr * p), sn, cs;
            sincosf(adi * p, &sn, &cs);
            *(short*)(lds + OFF_WR + swz(s, m * 2)) = f2bf(e * cs);
            *(short*)(lds + OFF_WI + swz(s, m * 2)) = f2bf(e * sn);
        }
    }
    {   // V[t][s] = 2 b_s w_s^(t+1):  Vr = Re, Vm = -Im
        int t = tid >> 2, s0 = (tid & 3) * 16;
        float p = (float)(t + 1);
        for (int s = s0; s < s0 + 16; ++s) {
            float e = expf(parF[s] * p), sn, cs;
            sincosf(parF[64 + s] * p, &sn, &cs);
            float vr = e * (parF[128 + s] * cs - parF[192 + s] * sn);
            float vi = e * (parF[128 + s] * sn + parF[192 + s] * cs);
            *(short*)(lds + OFF_VR + swz(t, s * 2)) = f2bf(vr);
            *(short*)(lds + OFF_VM + swz(t, s * 2)) = f2bf(-vi);
        }
    }
    // zero Hr+Hi (4096 B, 16 B per thread)
    *(f32x4*)(lds + OFF_HR + tid * 16) = f32x4{0.f, 0.f, 0.f, 0.f};

    // stage X chunk 0: thread -> (b = tid>>4, m0 = (tid&15)*4)
    const float* xbase = x + ((size_t)(tid >> 4) * NC + c) * NL + (tid & 15) * 4;
    {
        float4 pf = *(const float4*)xbase;
        short4v xp = {f2bf(pf.x), f2bf(pf.y), f2bf(pf.z), f2bf(pf.w)};
        *(short4v*)(lds + OFF_X + swz(tid >> 4, (tid & 15) * 8)) = xp;
    }

    // per-lane w^Q for the 4 owned s-rows of the D/H fragment
    float wQr[4], wQi[4], Hr[4] = {0, 0, 0, 0}, Hi[4] = {0, 0, 0, 0};
#pragma unroll
    for (int j = 0; j < 4; ++j) {
        int s = 16 * w + (l >> 4) * 4 + j;
        float e = expf(64.0f * parF[s]), sn, cs;
        sincosf(64.0f * parF[64 + s], &sn, &cs);
        wQr[j] = e * cs; wQi[j] = e * sn;
    }
    __syncthreads();

    // ---- hoist constant A-frags into registers ----
    const int ar_ = l & 15;          // A row within 16-tile / B col (=batch)
    const int kb  = (l >> 4) * 16;   // k-group byte offset within row
    const int rT = 16 * w + ar_;     // this wave's A-row (t or s tile)
    bf16x8 tA0 = *(const bf16x8*)(lds + OFF_T  + swz(rT, kb));
    bf16x8 tA1 = *(const bf16x8*)(lds + OFF_T  + swz(rT, kb + 64));
    bf16x8 wrA0 = *(const bf16x8*)(lds + OFF_WR + swz(rT, kb));
    bf16x8 wrA1 = *(const bf16x8*)(lds + OFF_WR + swz(rT, kb + 64));
    bf16x8 wiA0 = *(const bf16x8*)(lds + OFF_WI + swz(rT, kb));
    bf16x8 wiA1 = *(const bf16x8*)(lds + OFF_WI + swz(rT, kb + 64));
    bf16x8 vrA0 = *(const bf16x8*)(lds + OFF_VR + swz(rT, kb));
    bf16x8 vrA1 = *(const bf16x8*)(lds + OFF_VR + swz(rT, kb + 64));
    bf16x8 vmA0 = *(const bf16x8*)(lds + OFF_VM + swz(rT, kb));
    bf16x8 vmA1 = *(const bf16x8*)(lds + OFF_VM + swz(rT, kb + 64));

    const char* xB0  = lds + OFF_X  + swz(ar_, kb);
    const char* xB1  = lds + OFF_X  + swz(ar_, kb + 64);
    const char* hrB0 = lds + OFF_HR + swz(ar_, kb);
    const char* hrB1 = lds + OFF_HR + swz(ar_, kb + 64);
    const char* hiB0 = lds + OFF_HI + swz(ar_, kb);
    const char* hiB1 = lds + OFF_HI + swz(ar_, kb + 64);

    float* ybase = y + ((size_t)ar_ * NC + c) * NL + 16 * w + (l >> 4) * 4;

    // ---- main chunk loop ----
    for (int q = 0; q < NQ; ++q) {
        const int l0 = q * Q;
        // prefetch next chunk (clamped at the end; value unused then)
        float4 pf = *(const float4*)(xbase + ((q < NQ - 1) ? l0 + Q : 0));

        bf16x8 xb0 = *(const bf16x8*)xB0;
        bf16x8 xb1 = *(const bf16x8*)xB1;
        bf16x8 hr0 = *(const bf16x8*)hrB0;
        bf16x8 hr1 = *(const bf16x8*)hrB1;
        bf16x8 hi0 = *(const bf16x8*)hiB0;
        bf16x8 hi1 = *(const bf16x8*)hiB1;

        f32x4 yacc = {0.f, 0.f, 0.f, 0.f};
        f32x4 dr   = {0.f, 0.f, 0.f, 0.f};
        f32x4 di   = {0.f, 0.f, 0.f, 0.f};

        // y = T@X + Vr@Hr + Vm@Hi   (uses OLD H)
        yacc = __builtin_amdgcn_mfma_f32_16x16x32_bf16(tA0, xb0, yacc, 0, 0, 0);
        yacc = __builtin_amdgcn_mfma_f32_16x16x32_bf16(tA1, xb1, yacc, 0, 0, 0);
        yacc = __builtin_amdgcn_mfma_f32_16x16x32_bf16(vrA0, hr0, yacc, 0, 0, 0);
        yacc = __builtin_amdgcn_mfma_f32_16x16x32_bf16(vrA1, hr1, yacc, 0, 0, 0);
        yacc = __builtin_amdgcn_mfma_f32_16x16x32_bf16(vmA0, hi0, yacc, 0, 0, 0);
        yacc = __builtin_amdgcn_mfma_f32_16x16x32_bf16(vmA1, hi1, yacc, 0, 0, 0);
        // D = W@X
        dr = __builtin_amdgcn_mfma_f32_16x16x32_bf16(wrA0, xb0, dr, 0, 0, 0);
        dr = __builtin_amdgcn_mfma_f32_16x16x32_bf16(wrA1, xb1, dr, 0, 0, 0);
        di = __builtin_amdgcn_mfma_f32_16x16x32_bf16(wiA0, xb0, di, 0, 0, 0);
        di = __builtin_amdgcn_mfma_f32_16x16x32_bf16(wiA1, xb1, di, 0, 0, 0);

        // H <- w^Q * H + D  (fp32, registers)
#pragma unroll
        for (int j = 0; j < 4; ++j) {
            float nr = wQr[j] * Hr[j] - wQi[j] * Hi[j] + dr[j];
            float ni = wQr[j] * Hi[j] + wQi[j] * Hr[j] + di[j];
            Hr[j] = nr; Hi[j] = ni;
        }

        __syncthreads();   // all waves done reading X_q and H old

        // write new H (bf16) for next chunk's inter GEMM
        short4v hrp = {f2bf(Hr[0]), f2bf(Hr[1]), f2bf(Hr[2]), f2bf(Hr[3])};
        short4v hip2 = {f2bf(Hi[0]), f2bf(Hi[1]), f2bf(Hi[2]), f2bf(Hi[3])};
        *(short4v*)(lds + OFF_HR + swz(ar_, 32 * w + (l >> 4) * 8)) = hrp;
        *(short4v*)(lds + OFF_HI + swz(ar_, 32 * w + (l >> 4) * 8)) = hip2;

        // write X_{q+1}
        short4v xpn = {f2bf(pf.x), f2bf(pf.y), f2bf(pf.z), f2bf(pf.w)};
        *(short4v*)(lds + OFF_X + swz(tid >> 4, (tid & 15) * 8)) = xpn;

        // store y chunk: lane's 4 consecutive t at col b=ar_
        *(f32x4*)(ybase + l0) = yacc;

        __syncthreads();   // H/X visible before next chunk reads
    }
}

extern "C" void kernel_launch(void* const* d_in, const int* in_sizes, int n_in,
                              void* d_out, int out_size, void* d_ws, size_t ws_size,
                              hipStream_t stream) {
    const float* x      = (const float*)d_in[0];
    const float* log_dt = (const float*)d_in[1];
    const float* a_real = (const float*)d_in[2];
    const float* a_imag = (const float*)d_in[3];
    const float* cv     = (const float*)d_in[4];
    float* yv = (float*)d_out;

    hipLaunchKernelGGL(s4d_mfma, dim3(NC), dim3(256), 0, stream,
                       x, log_dt, a_real, a_imag, cv, yv);
}

// Round 5
// 168.291 us; speedup vs baseline: 1.9705x; 1.0028x over previous
//
#include <hip/hip_runtime.h>

typedef __attribute__((ext_vector_type(8))) short bf16x8;
typedef __attribute__((ext_vector_type(4))) short short4v;
typedef __attribute__((ext_vector_type(4))) float f32x4;

#define NB 16
#define NC 256
#define NS 64
#define NL 4096
#define Q  64
#define NQ (NL / Q)

// LDS byte offsets
#define OFF_T   0        // 64x64 bf16 [t][m]   (A-operand, swizzled)
#define OFF_WR  8192     // 64x64 bf16 [s][m]
#define OFF_WI  16384
#define OFF_VR  24576    // 64x64 bf16 [t][s]
#define OFF_VM  32768
#define OFF_X   40960    // 16x64 bf16 [b][m]   (B-operand, swizzled)
#define OFF_HR  43008    // 16x64 bf16 [b][s]
#define OFF_HI  45056
#define OFF_PAR 47104    // adr[64], adi[64], b2r[64], b2i[64]
#define OFF_K   48128    // k[64]
#define OFF_KP  48384    // kpart[8][64]
#define LDS_SZ  50432

__device__ __forceinline__ int swz(int row, int bytecol) {
    return (row * 128 + bytecol) ^ ((row & 7) << 4);
}
__device__ __forceinline__ short f2bf(float f) {            // RNE float->bf16
    unsigned u = __builtin_bit_cast(unsigned, f);
    u = (u + 0x7FFFu + ((u >> 16) & 1u)) >> 16;
    return (short)u;
}

__global__ __launch_bounds__(512, 1) void s4d_mfma(const float* __restrict__ x,
                                                   const float* __restrict__ log_dt,
                                                   const float* __restrict__ a_real,
                                                   const float* __restrict__ a_imag,
                                                   const float* __restrict__ cv,
                                                   float* __restrict__ y) {
    __shared__ __align__(16) char lds[LDS_SZ];
    const int c = blockIdx.x;
    const int tid = threadIdx.x;
    const int l = tid & 63, w = tid >> 6;    // 8 waves
    const bool isY = (w < 4);                // waves 0-3: y GEMMs; 4-7: D/state/staging
    const int wl = w & 3;                    // 16-row tile index within role

    float* parF = (float*)(lds + OFF_PAR);
    float* kF   = (float*)(lds + OFF_K);
    float* kpF  = (float*)(lds + OFF_KP);

    // ---- stage 0: per-s params (identical arithmetic to verified version) ----
    if (tid < 64) {
        int s = tid;
        float dt = expf(log_dt[c]);
        float ar = -expf(a_real[c * 64 + s]);
        float ai = a_imag[c * 64 + s];
        float adr = ar * dt, adi = ai * dt;
        float e = expf(adr), sn, cs;
        sincosf(adi, &sn, &cs);
        float wr = e * cs, wi = e * sn;
        float inv = 1.0f / (ar * ar + ai * ai);
        float numr = wr - 1.0f, numi = wi;
        float qr = (numr * ar + numi * ai) * inv;
        float qi = (numi * ar - numr * ai) * inv;
        float c0 = cv[2 * (c * 64 + s)], c1 = cv[2 * (c * 64 + s) + 1];
        float br = c0 * qr - c1 * qi;
        float bi = c0 * qi + c1 * qr;
        parF[s] = adr; parF[64 + s] = adi;
        parF[128 + s] = 2.0f * br; parF[192 + s] = 2.0f * bi;
    }
    __syncthreads();

    // ---- stage 1: k[d] = sum_s 2Re(b_s w_s^d), 8-way partials over s ----
    {
        int d = tid & 63, part = tid >> 6;
        float ps = 0.0f;
        for (int s = part * 8; s < part * 8 + 8; ++s) {
            float e = expf(parF[s] * (float)d), sn, cs;
            sincosf(parF[64 + s] * (float)d, &sn, &cs);
            ps += e * (parF[128 + s] * cs - parF[192 + s] * sn);
        }
        kpF[part * 64 + d] = ps;
    }
    __syncthreads();
    if (tid < 64) {
        float a = 0.0f;
#pragma unroll
        for (int p = 0; p < 8; ++p) a += kpF[p * 64 + tid];
        kF[tid] = a;
    }
    __syncthreads();

    // ---- stage 2: fill T, W, V; zero H; stage X0 ----
    {   // T[t][m] = k[t-m] (t>=m) else 0
        int t = tid >> 3, m0 = (tid & 7) * 8;
        for (int m = m0; m < m0 + 8; ++m) {
            float v = (t >= m) ? kF[t - m] : 0.0f;
            *(short*)(lds + OFF_T + swz(t, m * 2)) = f2bf(v);
        }
    }
    {   // W[s][m] = w_s^(63-m)
        int s = tid >> 3, m0 = (tid & 7) * 8;
        float adr = parF[s], adi = parF[64 + s];
        for (int m = m0; m < m0 + 8; ++m) {
            float p = (float)(63 - m);
            float e = expf(adr * p), sn, cs;
            sincosf(adi * p, &sn, &cs);
            *(short*)(lds + OFF_WR + swz(s, m * 2)) = f2bf(e * cs);
            *(short*)(lds + OFF_WI + swz(s, m * 2)) = f2bf(e * sn);
        }
    }
    {   // V[t][s] = 2 b_s w_s^(t+1):  Vr = Re, Vm = -Im
        int t = tid >> 3, s0 = (tid & 7) * 8;
        float p = (float)(t + 1);
        for (int s = s0; s < s0 + 8; ++s) {
            float e = expf(parF[s] * p), sn, cs;
            sincosf(parF[64 + s] * p, &sn, &cs);
            float vr = e * (parF[128 + s] * cs - parF[192 + s] * sn);
            float vi = e * (parF[128 + s] * sn + parF[192 + s] * cs);
            *(short*)(lds + OFF_VR + swz(t, s * 2)) = f2bf(vr);
            *(short*)(lds + OFF_VM + swz(t, s * 2)) = f2bf(-vi);
        }
    }
    if (tid < 256) {  // zero Hr+Hi (4096 B)
        *(f32x4*)(lds + OFF_HR + tid * 16) = f32x4{0.f, 0.f, 0.f, 0.f};
    }

    const int ltid = tid - 256;              // D-wave staging index
    const float* xbase = nullptr;
    if (!isY) {
        xbase = x + ((size_t)(ltid >> 4) * NC + c) * NL + (ltid & 15) * 4;
        float4 p0 = *(const float4*)xbase;   // stage X chunk 0
        short4v xp = {f2bf(p0.x), f2bf(p0.y), f2bf(p0.z), f2bf(p0.w)};
        *(short4v*)(lds + OFF_X + swz(ltid >> 4, (ltid & 15) * 8)) = xp;
    }

    const int ar_ = l & 15;          // A row within 16-tile / B col (=batch)
    const int kb  = (l >> 4) * 16;   // k-group byte offset within row
    const int rT  = 16 * wl + ar_;   // this wave's A-row

    // role-specific constant A-frags + state
    bf16x8 tA0, tA1, vrA0, vrA1, vmA0, vmA1;     // y role
    bf16x8 wrA0, wrA1, wiA0, wiA1;               // D role
    float wQr[4], wQi[4], Hr[4] = {0, 0, 0, 0}, Hi[4] = {0, 0, 0, 0};
    float4 pfA = {0.f, 0.f, 0.f, 0.f};

    if (!isY) {
#pragma unroll
        for (int j = 0; j < 4; ++j) {            // per-lane w^Q for owned s-rows
            int s = 16 * wl + (l >> 4) * 4 + j;
            float e = expf(64.0f * parF[s]), sn, cs;
            sincosf(64.0f * parF[64 + s], &sn, &cs);
            wQr[j] = e * cs; wQi[j] = e * sn;
        }
        pfA = *(const float4*)(xbase + Q);       // prefetch chunk 1
    }
    __syncthreads();

    if (isY) {
        tA0  = *(const bf16x8*)(lds + OFF_T  + swz(rT, kb));
        tA1  = *(const bf16x8*)(lds + OFF_T  + swz(rT, kb + 64));
        vrA0 = *(const bf16x8*)(lds + OFF_VR + swz(rT, kb));
        vrA1 = *(const bf16x8*)(lds + OFF_VR + swz(rT, kb + 64));
        vmA0 = *(const bf16x8*)(lds + OFF_VM + swz(rT, kb));
        vmA1 = *(const bf16x8*)(lds + OFF_VM + swz(rT, kb + 64));
    } else {
        wrA0 = *(const bf16x8*)(lds + OFF_WR + swz(rT, kb));
        wrA1 = *(const bf16x8*)(lds + OFF_WR + swz(rT, kb + 64));
        wiA0 = *(const bf16x8*)(lds + OFF_WI + swz(rT, kb));
        wiA1 = *(const bf16x8*)(lds + OFF_WI + swz(rT, kb + 64));
    }

    float* ybase = y + ((size_t)ar_ * NC + c) * NL + 16 * wl + (l >> 4) * 4;

    // ---- main chunk loop ----
    for (int q = 0; q < NQ; ++q) {
        float4 pfB = {0.f, 0.f, 0.f, 0.f};
        if (!isY) // prefetch chunk q+2 (clamped; value dead past the end)
            pfB = *(const float4*)(xbase + ((q < NQ - 2) ? (q + 2) * Q : 0));

        if (isY) {
            bf16x8 xb0 = *(const bf16x8*)(lds + OFF_X  + swz(ar_, kb));
            bf16x8 xb1 = *(const bf16x8*)(lds + OFF_X  + swz(ar_, kb + 64));
            bf16x8 hr0 = *(const bf16x8*)(lds + OFF_HR + swz(ar_, kb));
            bf16x8 hr1 = *(const bf16x8*)(lds + OFF_HR + swz(ar_, kb + 64));
            bf16x8 hi0 = *(const bf16x8*)(lds + OFF_HI + swz(ar_, kb));
            bf16x8 hi1 = *(const bf16x8*)(lds + OFF_HI + swz(ar_, kb + 64));
            // 3 independent 2-deep chains
            f32x4 aT = {0.f, 0.f, 0.f, 0.f};
            f32x4 aR = {0.f, 0.f, 0.f, 0.f};
            f32x4 aM = {0.f, 0.f, 0.f, 0.f};
            aT = __builtin_amdgcn_mfma_f32_16x16x32_bf16(tA0,  xb0, aT, 0, 0, 0);
            aR = __builtin_amdgcn_mfma_f32_16x16x32_bf16(vrA0, hr0, aR, 0, 0, 0);
            aM = __builtin_amdgcn_mfma_f32_16x16x32_bf16(vmA0, hi0, aM, 0, 0, 0);
            aT = __builtin_amdgcn_mfma_f32_16x16x32_bf16(tA1,  xb1, aT, 0, 0, 0);
            aR = __builtin_amdgcn_mfma_f32_16x16x32_bf16(vrA1, hr1, aR, 0, 0, 0);
            aM = __builtin_amdgcn_mfma_f32_16x16x32_bf16(vmA1, hi1, aM, 0, 0, 0);
            f32x4 yacc = (aT + aR) + aM;
            *(f32x4*)(ybase + q * Q) = yacc;     // issue store early
        } else {
            bf16x8 xb0 = *(const bf16x8*)(lds + OFF_X + swz(ar_, kb));
            bf16x8 xb1 = *(const bf16x8*)(lds + OFF_X + swz(ar_, kb + 64));
            f32x4 dr = {0.f, 0.f, 0.f, 0.f};
            f32x4 di = {0.f, 0.f, 0.f, 0.f};
            dr = __builtin_amdgcn_mfma_f32_16x16x32_bf16(wrA0, xb0, dr, 0, 0, 0);
            di = __builtin_amdgcn_mfma_f32_16x16x32_bf16(wiA0, xb0, di, 0, 0, 0);
            dr = __builtin_amdgcn_mfma_f32_16x16x32_bf16(wrA1, xb1, dr, 0, 0, 0);
            di = __builtin_amdgcn_mfma_f32_16x16x32_bf16(wiA1, xb1, di, 0, 0, 0);
            // H <- w^Q * H + D  (fp32 registers, owned by D-waves only)
#pragma unroll
            for (int j = 0; j < 4; ++j) {
                float nr = wQr[j] * Hr[j] - wQi[j] * Hi[j] + dr[j];
                float ni = wQr[j] * Hi[j] + wQi[j] * Hr[j] + di[j];
                Hr[j] = nr; Hi[j] = ni;
            }
        }

        __syncthreads();   // all reads of X_q / H_q complete

        if (!isY) {
            if (q < NQ - 1) {
                short4v hrp = {f2bf(Hr[0]), f2bf(Hr[1]), f2bf(Hr[2]), f2bf(Hr[3])};
                short4v hip2 = {f2bf(Hi[0]), f2bf(Hi[1]), f2bf(Hi[2]), f2bf(Hi[3])};
                *(short4v*)(lds + OFF_HR + swz(ar_, 32 * wl + (l >> 4) * 8)) = hrp;
                *(short4v*)(lds + OFF_HI + swz(ar_, 32 * wl + (l >> 4) * 8)) = hip2;
                short4v xpn = {f2bf(pfA.x), f2bf(pfA.y), f2bf(pfA.z), f2bf(pfA.w)};
                *(short4v*)(lds + OFF_X + swz(ltid >> 4, (ltid & 15) * 8)) = xpn;
            }
            pfA = pfB;
        }

        __syncthreads();   // X_{q+1}/H_{q+1} visible
    }
}

extern "C" void kernel_launch(void* const* d_in, const int* in_sizes, int n_in,
                              void* d_out, int out_size, void* d_ws, size_t ws_size,
                              hipStream_t stream) {
    const float* x      = (const float*)d_in[0];
    const float* log_dt = (const float*)d_in[1];
    const float* a_real = (const float*)d_in[2];
    const float* a_imag = (const float*)d_in[3];
    const float* cv     = (const float*)d_in[4];
    float* yv = (float*)d_out;

    hipLaunchKernelGGL(s4d_mfma, dim3(NC), dim3(512), 0, stream,
                       x, log_dt, a_real, a_imag, cv, yv);
}